// Round 4
// baseline (665.775 us; speedup 1.0000x reference)
//
#include <hip/hip_runtime.h>
#include <math.h>

#define NEG_SLOPE 0.2f

__device__ __forceinline__ float lrelu(float x) {
    return fmaxf(x, NEG_SLOPE * x);
}

constexpr int clog2(int n) { return (n <= 1) ? 0 : 1 + clog2(n / 2); }

// Fused conv3d(3x3x3,pad=1) + bias + maxpool(2x2x2) + LeakyReLU, LDS-staged.
// v4: conflict-free float2 LDS reads (lane x-stride = one float2), sliding
// z-plane compute (plane p feeds (u=p-kz) accumulators; live set = 24 floats),
// float2 fill, XR=S+6 / XOFF=2 for smaller LDS.
// Mapping: 256 threads = BPB * (CO/CPT) * ((ZT/PZT)*SP*SP).
template<int CI, int CO, int S, int ZT, int PZT, int CPT, int BPB>
__global__ __launch_bounds__(256) void conv_pool_lds3(
    const float* __restrict__ in,   // [B, CI, S,S,S]
    const float* __restrict__ w,    // [CO, CI, 3,3,3]
    const float* __restrict__ bias, // [CO]
    float* __restrict__ out,        // [B, CO, SP,SP,SP]
    int B)
{
    constexpr int SP     = S / 2;
    constexpr int ZD     = 2 * ZT + 2;       // staged z planes incl halo
    constexpr int YS     = S + 2;            // rows incl y-halo
    constexpr int XOFF   = 2;                // x = gx + XOFF
    constexpr int XR     = S + 6;            // row stride (even)
    constexpr int XRH    = XR / 2;
    constexpr int PLANE  = YS * XR;
    constexpr int PLANE2 = PLANE / 2;
    constexpr int NPAIR  = BPB * CI * ZD;    // staged planes
    constexpr int LDS_N  = NPAIR * PLANE;
    constexpr int NOG    = CO / CPT;
    constexpr int NZB    = ZT / PZT;
    constexpr int NPOS   = NZB * SP * SP;
    constexpr int NSLAB  = SP / ZT;
    constexpr int PLN    = 2 * PZT + 2;      // planes consumed per thread
    static_assert(BPB * NOG * NPOS == 256, "thread mapping must cover block");
    static_assert((LDS_N & 3) == 0, "float4 zero");

    __shared__ __align__(16) float sm[LDS_N];

    const int t     = threadIdx.x;
    const int zslab = blockIdx.x & (NSLAB - 1);
    const int b0    = (blockIdx.x >> clog2(NSLAB)) * BPB;
    const int zp0   = zslab * ZT;
    const int gz0   = 2 * zp0 - 1;           // global z of staged plane 0

    // ---- Phase A: zero LDS (halos + out-of-range planes) ----
    {
        float4* s4 = (float4*)sm;
        constexpr int N4 = LDS_N / 4;
#pragma unroll
        for (int i = 0; i < (N4 + 255) / 256; ++i) {
            const int k = t + i * 256;
            if (k < N4) s4[k] = make_float4(0.f, 0.f, 0.f, 0.f);
        }
    }
    __syncthreads();

    // ---- Phase B: interior rows, float2 global -> float2 LDS ----
    {
        constexpr int CH    = S / 2;             // float2 chunks per row
        constexpr int PJOBS = S * CH;            // jobs per plane (pow2)
        constexpr int ITERS = NPAIR * PJOBS / 256;
        static_assert(ITERS * 256 == NPAIR * PJOBS, "exact fill");
        float2* s2w = (float2*)sm;
#pragma unroll
        for (int it = 0; it < ITERS; ++it) {
            const int i     = t + it * 256;
            const int idx   = i & (PJOBS - 1);
            const int plane = i >> clog2(PJOBS); // (bl*CI+ci)*ZD + z
            const int cc    = idx & (CH - 1);
            const int yy    = idx >> clog2(CH);
            const int z     = plane % ZD;        // const divisor -> magic mul
            const int bci   = plane / ZD;
            const int gz    = gz0 + z;
            if ((unsigned)gz < (unsigned)S) {
                const float2 v = *(const float2*)&in[
                    ((long)(b0 * CI + bci) * S + gz) * (S * S) + yy * S + 2 * cc];
                s2w[(plane * YS + yy + 1) * XRH + 1 + cc] = v;
            }
        }
    }
    __syncthreads();

    // ---- Compute: sliding staged planes ----
    const int pos = t & (NPOS - 1);
    const int og  = (t >> clog2(NPOS)) & (NOG - 1);
    const int bl  = t >> clog2(NPOS * NOG);
    const int xp  = pos & (SP - 1);
    const int yp  = (pos >> clog2(SP)) & (SP - 1);
    const int zb  = pos >> (2 * clog2(SP));
    const int z0  = 2 * zb * PZT;            // first staged plane this thread

    float acc[PZT][CPT][8];
#pragma unroll
    for (int zi = 0; zi < PZT; ++zi)
#pragma unroll
        for (int oo = 0; oo < CPT; ++oo)
#pragma unroll
            for (int p = 0; p < 8; ++p) acc[zi][oo][p] = 0.f;

    const float2* s2 = (const float2*)sm;
    const int rbase = yp * XR + xp;          // float2 units within plane

#pragma unroll 1
    for (int ci = 0; ci < CI; ++ci) {
        const int cbase = ((bl * CI + ci) * ZD + z0) * PLANE2 + rbase;
#pragma unroll
        for (int p = 0; p < PLN; ++p) {
            // 4 rows x 6 floats (use f[1..4]); even bases -> ds_read_b64,
            // lane stride = 1 float2 -> conflict-free
            float r[4][6];
#pragma unroll
            for (int dy = 0; dy < 4; ++dy) {
                const int a = cbase + p * PLANE2 + dy * XRH;
                const float2 q0 = s2[a];
                const float2 q1 = s2[a + 1];
                const float2 q2 = s2[a + 2];
                r[dy][0] = q0.x; r[dy][1] = q0.y;
                r[dy][2] = q1.x; r[dy][3] = q1.y;
                r[dy][4] = q2.x; r[dy][5] = q2.y;
            }
#pragma unroll
            for (int kz = 0; kz < 3; ++kz) {
                const int u = p - kz;                    // unpooled z in tile
                if (u >= 0 && u < 2 * PZT) {
                    const int zi = u >> 1, pz = u & 1;
#pragma unroll
                    for (int oo = 0; oo < CPT; ++oo) {
                        const float* wp = w +
                            (long)((og * CPT + oo) * CI + ci) * 27 + kz * 9;
#pragma unroll
                        for (int ky = 0; ky < 3; ++ky)
#pragma unroll
                            for (int kx = 0; kx < 3; ++kx) {
                                const float wv = wp[ky * 3 + kx];
#pragma unroll
                                for (int py = 0; py < 2; ++py)
#pragma unroll
                                    for (int px = 0; px < 2; ++px)
                                        acc[zi][oo][pz * 4 + py * 2 + px] +=
                                            r[py + ky][px + kx + 1] * wv;
                            }
                    }
                }
            }
        }
    }

    // ---- Epilogue: pool-max + bias + lrelu + store ----
#pragma unroll
    for (int zi = 0; zi < PZT; ++zi)
#pragma unroll
        for (int oo = 0; oo < CPT; ++oo) {
            const int o = og * CPT + oo;
            float m = acc[zi][oo][0];
#pragma unroll
            for (int p = 1; p < 8; ++p) m = fmaxf(m, acc[zi][oo][p]);
            m += bias[o];
            out[(long)((b0 + bl) * CO + o) * (SP * SP * SP) +
                ((zp0 + zb * PZT + zi) * SP + yp) * SP + xp] = lrelu(m);
        }
}

// Layer 5: CI=32, S=2 -> out [B,64]. 4 batches per block; region reads are
// wave-uniform -> LDS broadcast, conflict-free.
__global__ __launch_bounds__(256) void conv_pool_lrelu_l5(
    const float* __restrict__ in,   // [B,32,2,2,2]
    const float* __restrict__ w,    // [64,32,3,3,3]
    const float* __restrict__ bias, // [64]
    float* __restrict__ out,        // [B,64]
    int B)
{
    constexpr int CI = 32;
    __shared__ float sm[4 * CI * 64];
    const int t = threadIdx.x;
    const int b0 = blockIdx.x * 4;

    for (int i = t; i < 4 * CI * 64; i += 256) {
        const int x = i % 4;
        const int y = (i / 4) % 4;
        const int z = (i / 16) % 4;
        const int ci = (i / 64) % CI;
        const int bl = i / (64 * CI);
        const int gx = x - 1, gy = y - 1, gz = z - 1;
        float v = 0.f;
        if ((unsigned)gx < 2u && (unsigned)gy < 2u && (unsigned)gz < 2u)
            v = in[((b0 + bl) * CI + ci) * 8 + (gz * 2 + gy) * 2 + gx];
        sm[i] = v;
    }
    __syncthreads();

    const int co = t % 64;
    const int bl = t / 64;
    float acc[8];
#pragma unroll
    for (int p = 0; p < 8; ++p) acc[p] = 0.f;

#pragma unroll 1
    for (int ci = 0; ci < CI; ++ci) {
        const float* sp_ = &sm[(bl * CI + ci) * 64];
        float v[4][4][4];
#pragma unroll
        for (int dz = 0; dz < 4; ++dz)
#pragma unroll
            for (int dy = 0; dy < 4; ++dy)
#pragma unroll
                for (int dx = 0; dx < 4; ++dx)
                    v[dz][dy][dx] = sp_[(dz * 4 + dy) * 4 + dx];
        const float* wp = w + (long)(co * CI + ci) * 27;
#pragma unroll
        for (int kz = 0; kz < 3; ++kz)
#pragma unroll
            for (int ky = 0; ky < 3; ++ky)
#pragma unroll
                for (int kx = 0; kx < 3; ++kx) {
                    const float wv = wp[kz * 9 + ky * 3 + kx];
#pragma unroll
                    for (int pz = 0; pz < 2; ++pz)
#pragma unroll
                        for (int py = 0; py < 2; ++py)
#pragma unroll
                            for (int px = 0; px < 2; ++px)
                                acc[pz * 4 + py * 2 + px] +=
                                    v[pz + kz][py + ky][px + kx] * wv;
                }
    }

    float m = acc[0];
#pragma unroll
    for (int p = 1; p < 8; ++p) m = fmaxf(m, acc[p]);
    m += bias[co];
    out[(b0 + bl) * 64 + co] = lrelu(m);
}

// 6 parallel heads: [B,64] -> 32 -> 16 -> 4, lrelu each, then L2-normalize.
__global__ __launch_bounds__(256) void fc_heads(
    const float* __restrict__ feat,
    const float* __restrict__ W1, const float* __restrict__ b1,
    const float* __restrict__ W2, const float* __restrict__ b2,
    const float* __restrict__ W3, const float* __restrict__ b3,
    float* __restrict__ out, int B)
{
    const int tid = blockIdx.x * 256 + threadIdx.x;
    if (tid >= 6 * B) return;
    const int b = tid % B;
    const int h = tid / B;

    float f[64];
#pragma unroll
    for (int k = 0; k < 64; ++k) f[k] = feat[b * 64 + k];

    float h1[32];
#pragma unroll 1
    for (int j = 0; j < 32; ++j) {
        float s = b1[h * 32 + j];
#pragma unroll
        for (int k = 0; k < 64; ++k) s += f[k] * W1[(h * 64 + k) * 32 + j];
        h1[j] = lrelu(s);
    }
    float h2[16];
#pragma unroll 1
    for (int j = 0; j < 16; ++j) {
        float s = b2[h * 16 + j];
#pragma unroll
        for (int k = 0; k < 32; ++k) s += h1[k] * W2[(h * 32 + k) * 16 + j];
        h2[j] = lrelu(s);
    }
    float h3[4];
#pragma unroll
    for (int j = 0; j < 4; ++j) {
        float s = b3[h * 4 + j];
#pragma unroll
        for (int k = 0; k < 16; ++k) s += h2[k] * W3[(h * 16 + k) * 4 + j];
        h3[j] = lrelu(s);
    }
    const float n = sqrtf(h3[0] * h3[0] + h3[1] * h3[1] +
                          h3[2] * h3[2] + h3[3] * h3[3]);
    const float inv = 1.f / n;
#pragma unroll
    for (int q = 0; q < 4; ++q) out[(b * 6 + h) * 4 + q] = h3[q] * inv;
}

extern "C" void kernel_launch(void* const* d_in, const int* in_sizes, int n_in,
                              void* d_out, int out_size, void* d_ws, size_t ws_size,
                              hipStream_t stream)
{
    const float* voxel = (const float*)d_in[0];
    const float* cw1 = (const float*)d_in[1];  const float* cb1 = (const float*)d_in[2];
    const float* cw2 = (const float*)d_in[3];  const float* cb2 = (const float*)d_in[4];
    const float* cw3 = (const float*)d_in[5];  const float* cb3 = (const float*)d_in[6];
    const float* cw4 = (const float*)d_in[7];  const float* cb4 = (const float*)d_in[8];
    const float* cw5 = (const float*)d_in[9];  const float* cb5 = (const float*)d_in[10];
    const float* W1  = (const float*)d_in[11]; const float* b1  = (const float*)d_in[12];
    const float* W2  = (const float*)d_in[13]; const float* b2  = (const float*)d_in[14];
    const float* W3  = (const float*)d_in[15]; const float* b3  = (const float*)d_in[16];
    float* out = (float*)d_out;

    const int B = 1024;
    float* buf1 = (float*)d_ws;              // [B,4,16^3]
    float* buf2 = buf1 + 16777216;           // [B,8,8^3]
    float* buf3 = buf2 + 4194304;            // [B,16,4^3]
    float* buf4 = buf3 + 1048576;            // [B,32,2^3]
    float* buf5 = buf4 + 262144;             // [B,64]

    // L1: 1->4, 32^3->16^3. ZT=2,PZT=2,CPT=4. LDS 31008 B -> 5 blk/CU
    conv_pool_lds3<1, 4, 32, 2, 2, 4, 1><<<1024 * 8, 256, 0, stream>>>(voxel, cw1, cb1, buf1, B);
    // L2: 4->8, 16^3->8^3. ZT=2,PZT=1,CPT=4. LDS 38016 B -> 4 blk/CU
    conv_pool_lds3<4, 8, 16, 2, 1, 4, 1><<<1024 * 4, 256, 0, stream>>>(buf1, cw2, cb2, buf2, B);
    // L3: 8->16, 8^3->4^3. ZT=4,PZT=1,CPT=4. LDS 44800 B -> 3 blk/CU
    conv_pool_lds3<8, 16, 8, 4, 1, 4, 1><<<1024, 256, 0, stream>>>(buf2, cw3, cb3, buf3, B);
    // L4: 16->32, 4^3->2^3. ZT=2,PZT=1,CPT=2,BPB=2. LDS 46080 B -> 3 blk/CU
    conv_pool_lds3<16, 32, 4, 2, 1, 2, 2><<<512, 256, 0, stream>>>(buf3, cw4, cb4, buf4, B);
    // L5: 32->64, 2^3->1. 4 b/block.
    conv_pool_lrelu_l5<<<256, 256, 0, stream>>>(buf4, cw5, cb5, buf5, B);
    // FC heads
    fc_heads<<<24, 256, 0, stream>>>(buf5, W1, b1, W2, b2, W3, b3, out, B);
}

// Round 5
// 574.879 us; speedup vs baseline: 1.1581x; 1.1581x over previous
//
#include <hip/hip_runtime.h>
#include <math.h>

#define NEG_SLOPE 0.2f

typedef _Float16 half2_t __attribute__((ext_vector_type(2)));

__device__ __forceinline__ float lrelu(float x) {
    return fmaxf(x, NEG_SLOPE * x);
}

__device__ __forceinline__ float fdot2(half2_t a, half2_t b, float c) {
#if __has_builtin(__builtin_amdgcn_fdot2)
    return __builtin_amdgcn_fdot2(a, b, c, false);
#else
    return c + (float)a.x * (float)b.x + (float)a.y * (float)b.y;
#endif
}

constexpr int clog2(int n) { return (n <= 1) ? 0 : 1 + clog2(n / 2); }

// ---------------------------------------------------------------------------
// Layer 1 (fp32 input, CI=1): EXACT round-3 structure (140us measured), only
// the epilogue changed: packs co-pairs to half2 for the f16 pipeline.
// ---------------------------------------------------------------------------
template<int CI, int CO, int S, int ZT, int PZT, int CPT, int BPB>
__global__ __launch_bounds__(256) void conv_pool_f32h(
    const float* __restrict__ in,   // [B, CI, S,S,S]
    const float* __restrict__ w,    // [CO, CI, 3,3,3]
    const float* __restrict__ bias, // [CO]
    half2_t* __restrict__ out,      // [B, CO/2, SP^3] channel-pair packed
    int B)
{
    constexpr int SP    = S / 2;
    constexpr int ZD    = 2 * ZT + 2;
    constexpr int YS    = S + 2;
    constexpr int XOFF  = 5;
    constexpr int XR    = S + 8;
    constexpr int PLANE = YS * XR;
    constexpr int NPAIR = BPB * CI * ZD;
    constexpr int LDS_N = NPAIR * PLANE;
    constexpr int NOG   = CO / CPT;
    constexpr int NZB   = ZT / PZT;
    constexpr int NPOS  = NZB * SP * SP;
    constexpr int NSLAB = SP / ZT;
    static_assert(BPB * NOG * NPOS == 256, "thread mapping must cover block");
    static_assert((LDS_N & 3) == 0, "float4 zero");
    static_assert((CPT & 1) == 0, "pack pairs");

    __shared__ __align__(16) float sm[LDS_N];

    const int t     = threadIdx.x;
    const int zslab = blockIdx.x & (NSLAB - 1);
    const int b0    = (blockIdx.x >> clog2(NSLAB)) * BPB;
    const int zp0   = zslab * ZT;
    const int gz0   = 2 * zp0 - 1;

    {   // Phase A: zero LDS
        float4* s4 = (float4*)sm;
        constexpr int N4 = LDS_N / 4;
#pragma unroll
        for (int i = 0; i < (N4 + 255) / 256; ++i) {
            const int k = t + i * 256;
            if (k < N4) s4[k] = make_float4(0.f, 0.f, 0.f, 0.f);
        }
    }
    __syncthreads();

    {   // Phase B: interior rows, float4 loads
        constexpr int CHUNKS = S / 4;
        constexpr int PJOBS  = S * CHUNKS;
        constexpr int PPI    = 256 / PJOBS;
        constexpr int FITER  = NPAIR / PPI;
        static_assert(FITER * PPI == NPAIR, "fill covers planes exactly");
        const int idx  = t & (PJOBS - 1);
        const int poff = t >> clog2(PJOBS);
        const int cc   = idx & (CHUNKS - 1);
        const int yy   = idx >> clog2(CHUNKS);
#pragma unroll
        for (int it = 0; it < FITER; ++it) {
            const int plane = it * PPI + poff;
            const int z     = plane % ZD;
            const int bci   = plane / ZD;
            const int gz    = gz0 + z;
            if ((unsigned)gz < (unsigned)S) {
                const float4 v = *(const float4*)&in[
                    ((long)(b0 * CI + bci) * S + gz) * (S * S) + yy * S + 4 * cc];
                float* sp = &sm[(plane * YS + (yy + 1)) * XR + XOFF + 4 * cc];
                sp[0] = v.x; sp[1] = v.y; sp[2] = v.z; sp[3] = v.w;
            }
        }
    }
    __syncthreads();

    const int pos = t & (NPOS - 1);
    const int og  = (t >> clog2(NPOS)) & (NOG - 1);
    const int bl  = t >> clog2(NPOS * NOG);
    const int xp  = pos & (SP - 1);
    const int yp  = (pos >> clog2(SP)) & (SP - 1);
    const int zb  = pos >> (2 * clog2(SP));

#pragma unroll
    for (int zi = 0; zi < PZT; ++zi) {
        const int zl = zb * PZT + zi;
        float acc[CPT][8];
#pragma unroll
        for (int oo = 0; oo < CPT; ++oo)
#pragma unroll
            for (int p = 0; p < 8; ++p) acc[oo][p] = 0.f;

#pragma unroll 1
        for (int ci = 0; ci < CI; ++ci) {
            const float* sp_ = &sm[((bl * CI + ci) * ZD + 2 * zl) * PLANE +
                                   (2 * yp) * XR + 2 * xp + (XOFF - 1)];
            float v[4][4][4];
#pragma unroll
            for (int dz = 0; dz < 4; ++dz)
#pragma unroll
                for (int dy = 0; dy < 4; ++dy)
#pragma unroll
                    for (int dx = 0; dx < 4; ++dx)
                        v[dz][dy][dx] = sp_[dz * PLANE + dy * XR + dx];
#pragma unroll
            for (int oo = 0; oo < CPT; ++oo) {
                const float* wp = w + (long)((og * CPT + oo) * CI + ci) * 27;
#pragma unroll
                for (int kz = 0; kz < 3; ++kz)
#pragma unroll
                    for (int ky = 0; ky < 3; ++ky)
#pragma unroll
                        for (int kx = 0; kx < 3; ++kx) {
                            const float wv = wp[kz * 9 + ky * 3 + kx];
#pragma unroll
                            for (int pz = 0; pz < 2; ++pz)
#pragma unroll
                                for (int py = 0; py < 2; ++py)
#pragma unroll
                                    for (int px = 0; px < 2; ++px)
                                        acc[oo][pz * 4 + py * 2 + px] +=
                                            v[pz + kz][py + ky][px + kx] * wv;
                        }
            }
        }

#pragma unroll
        for (int oo = 0; oo < CPT; oo += 2) {
            const int o = og * CPT + oo;
            float m0 = acc[oo][0], m1 = acc[oo + 1][0];
#pragma unroll
            for (int p = 1; p < 8; ++p) {
                m0 = fmaxf(m0, acc[oo][p]);
                m1 = fmaxf(m1, acc[oo + 1][p]);
            }
            half2_t hv;
            hv.x = (_Float16)lrelu(m0 + bias[o]);
            hv.y = (_Float16)lrelu(m1 + bias[o + 1]);
            out[(long)((b0 + bl) * (CO / 2) + (o >> 1)) * (SP * SP * SP) +
                ((zp0 + zl) * SP + yp) * SP + xp] = hv;
        }
    }
}

// ---------------------------------------------------------------------------
// Layers 2-4: same structure, half2 channel-pair data + v_dot2_f32_f16.
// One LDS word = one half2 = 2 input channels; spatial addressing identical
// to the f32 version with CI -> CIH = CI/2. Weights pre-packed [CO][CIH][27].
// ---------------------------------------------------------------------------
template<int CIH, int CO, int S, int ZT, int PZT, int CPT, int BPB>
__global__ __launch_bounds__(256) void conv_pool_h2(
    const half2_t* __restrict__ in,  // [B, CIH, S,S,S]
    const half2_t* __restrict__ wh,  // [CO, CIH, 27] packed pairs
    const float*  __restrict__ bias, // [CO]
    half2_t* __restrict__ out,       // [B, CO/2, SP^3]
    int B)
{
    constexpr int SP    = S / 2;
    constexpr int ZD    = 2 * ZT + 2;
    constexpr int YS    = S + 2;
    constexpr int XOFF  = 2;                 // even -> uint2 fill aligned
    constexpr int XR    = S + 6;             // even
    constexpr int PLANE = YS * XR;
    constexpr int NPAIR = BPB * CIH * ZD;
    constexpr int LDS_N = NPAIR * PLANE;     // words (half2 each)
    constexpr int NOG   = CO / CPT;
    constexpr int NZB   = ZT / PZT;
    constexpr int NPOS  = NZB * SP * SP;
    constexpr int NSLAB = SP / ZT;
    static_assert(BPB * NOG * NPOS == 256, "thread mapping must cover block");
    static_assert((LDS_N & 3) == 0, "uint4 zero");
    static_assert((CPT & 1) == 0, "pack pairs");

    __shared__ __align__(16) uint sm[LDS_N];
    const uint* inu = (const uint*)in;

    const int t     = threadIdx.x;
    const int zslab = blockIdx.x & (NSLAB - 1);
    const int b0    = (blockIdx.x >> clog2(NSLAB)) * BPB;
    const int zp0   = zslab * ZT;
    const int gz0   = 2 * zp0 - 1;

    {   // Phase A: zero LDS
        uint4* s4 = (uint4*)sm;
        constexpr int N4 = LDS_N / 4;
#pragma unroll
        for (int i = 0; i < (N4 + 255) / 256; ++i) {
            const int k = t + i * 256;
            if (k < N4) s4[k] = make_uint4(0, 0, 0, 0);
        }
    }
    __syncthreads();

    {   // Phase B: interior rows, uint2 (= 2 half2 x-positions) loads
        constexpr int CH    = S / 2;
        constexpr int PJOBS = S * CH;
        constexpr int ITERS = NPAIR * PJOBS / 256;
        static_assert(ITERS * 256 == NPAIR * PJOBS, "exact fill");
#pragma unroll
        for (int it = 0; it < ITERS; ++it) {
            const int i     = t + it * 256;
            const int idx   = i & (PJOBS - 1);
            const int plane = i >> clog2(PJOBS);   // (bl*CIH+cp)*ZD + z
            const int cc    = idx & (CH - 1);
            const int yy    = idx >> clog2(CH);
            const int z     = plane % ZD;
            const int bci   = plane / ZD;
            const int gz    = gz0 + z;
            if ((unsigned)gz < (unsigned)S) {
                const uint2 v = *(const uint2*)&inu[
                    ((long)(b0 * CIH + bci) * S + gz) * (S * S) + yy * S + 2 * cc];
                *(uint2*)&sm[(plane * YS + yy + 1) * XR + XOFF + 2 * cc] = v;
            }
        }
    }
    __syncthreads();

    const int pos = t & (NPOS - 1);
    const int og  = (t >> clog2(NPOS)) & (NOG - 1);
    const int bl  = t >> clog2(NPOS * NOG);
    const int xp  = pos & (SP - 1);
    const int yp  = (pos >> clog2(SP)) & (SP - 1);
    const int zb  = pos >> (2 * clog2(SP));

#pragma unroll
    for (int zi = 0; zi < PZT; ++zi) {
        const int zl = zb * PZT + zi;
        float acc[CPT][8];
#pragma unroll
        for (int oo = 0; oo < CPT; ++oo)
#pragma unroll
            for (int p = 0; p < 8; ++p) acc[oo][p] = 0.f;

#pragma unroll 1
        for (int cp = 0; cp < CIH; ++cp) {
            const uint* sp_ = &sm[((bl * CIH + cp) * ZD + 2 * zl) * PLANE +
                                  (2 * yp) * XR + 2 * xp + (XOFF - 1)];
            half2_t v[4][4][4];
#pragma unroll
            for (int dz = 0; dz < 4; ++dz)
#pragma unroll
                for (int dy = 0; dy < 4; ++dy)
#pragma unroll
                    for (int dx = 0; dx < 4; ++dx) {
                        union { uint u; half2_t h; } c;
                        c.u = sp_[dz * PLANE + dy * XR + dx];
                        v[dz][dy][dx] = c.h;
                    }
#pragma unroll
            for (int oo = 0; oo < CPT; ++oo) {
                const half2_t* wp = wh + (long)((og * CPT + oo) * CIH + cp) * 27;
#pragma unroll
                for (int kz = 0; kz < 3; ++kz)
#pragma unroll
                    for (int ky = 0; ky < 3; ++ky)
#pragma unroll
                        for (int kx = 0; kx < 3; ++kx) {
                            const half2_t wv = wp[kz * 9 + ky * 3 + kx];
#pragma unroll
                            for (int pz = 0; pz < 2; ++pz)
#pragma unroll
                                for (int py = 0; py < 2; ++py)
#pragma unroll
                                    for (int px = 0; px < 2; ++px)
                                        acc[oo][pz * 4 + py * 2 + px] =
                                            fdot2(v[pz + kz][py + ky][px + kx],
                                                  wv, acc[oo][pz * 4 + py * 2 + px]);
                        }
            }
        }

#pragma unroll
        for (int oo = 0; oo < CPT; oo += 2) {
            const int o = og * CPT + oo;
            float m0 = acc[oo][0], m1 = acc[oo + 1][0];
#pragma unroll
            for (int p = 1; p < 8; ++p) {
                m0 = fmaxf(m0, acc[oo][p]);
                m1 = fmaxf(m1, acc[oo + 1][p]);
            }
            half2_t hv;
            hv.x = (_Float16)lrelu(m0 + bias[o]);
            hv.y = (_Float16)lrelu(m1 + bias[o + 1]);
            out[(long)((b0 + bl) * (CO / 2) + (o >> 1)) * (SP * SP * SP) +
                ((zp0 + zl) * SP + yp) * SP + xp] = hv;
        }
    }
}

// ---------------------------------------------------------------------------
// Layer 5: CIH=16, S=2 -> feat [B,64] fp32. 4 batches/block, wave-uniform
// region reads (LDS broadcast), dot2 inner.
// ---------------------------------------------------------------------------
__global__ __launch_bounds__(256) void conv_pool_l5_h2(
    const half2_t* __restrict__ in,  // [B,16,2,2,2]
    const half2_t* __restrict__ wh,  // [64,16,27]
    const float*  __restrict__ bias, // [64]
    float* __restrict__ out,         // [B,64]
    int B)
{
    constexpr int CIH = 16;
    __shared__ uint sm[4 * CIH * 64];
    const uint* inu = (const uint*)in;
    const int t = threadIdx.x;
    const int b0 = blockIdx.x * 4;

#pragma unroll
    for (int k = 0; k < (4 * CIH * 64) / 256; ++k) {
        const int i  = t + k * 256;
        const int x  = i & 3;
        const int y  = (i >> 2) & 3;
        const int z  = (i >> 4) & 3;
        const int cp = (i >> 6) & (CIH - 1);
        const int bl = i >> (6 + clog2(CIH));
        uint v = 0;
        if ((unsigned)(x - 1) < 2u && (unsigned)(y - 1) < 2u &&
            (unsigned)(z - 1) < 2u)
            v = inu[((b0 + bl) * CIH + cp) * 8 +
                    (z - 1) * 4 + (y - 1) * 2 + (x - 1)];
        sm[i] = v;
    }
    __syncthreads();

    const int co = t & 63;
    const int bl = t >> 6;
    float acc[8];
#pragma unroll
    for (int p = 0; p < 8; ++p) acc[p] = 0.f;

#pragma unroll 1
    for (int cp = 0; cp < CIH; ++cp) {
        const uint* sp_ = &sm[(bl * CIH + cp) * 64];
        half2_t v[4][4][4];
#pragma unroll
        for (int dz = 0; dz < 4; ++dz)
#pragma unroll
            for (int dy = 0; dy < 4; ++dy)
#pragma unroll
                for (int dx = 0; dx < 4; ++dx) {
                    union { uint u; half2_t h; } c;
                    c.u = sp_[(dz * 4 + dy) * 4 + dx];
                    v[dz][dy][dx] = c.h;
                }
        const half2_t* wp = wh + (long)(co * CIH + cp) * 27;
#pragma unroll
        for (int kz = 0; kz < 3; ++kz)
#pragma unroll
            for (int ky = 0; ky < 3; ++ky)
#pragma unroll
                for (int kx = 0; kx < 3; ++kx) {
                    const half2_t wv = wp[kz * 9 + ky * 3 + kx];
#pragma unroll
                    for (int pz = 0; pz < 2; ++pz)
#pragma unroll
                        for (int py = 0; py < 2; ++py)
#pragma unroll
                            for (int px = 0; px < 2; ++px)
                                acc[pz * 4 + py * 2 + px] =
                                    fdot2(v[pz + kz][py + ky][px + kx], wv,
                                          acc[pz * 4 + py * 2 + px]);
                }
    }

    float m = acc[0];
#pragma unroll
    for (int p = 1; p < 8; ++p) m = fmaxf(m, acc[p]);
    m += bias[co];
    out[(b0 + bl) * 64 + co] = lrelu(m);
}

// ---------------------------------------------------------------------------
// Weight pre-pack: fp32 [CO][CI][27] -> half2 [CO][CI/2][27] (pairs over ci).
// ---------------------------------------------------------------------------
__device__ __forceinline__ void pack_one(int i, const float* w, uint* h,
                                         int CO, int CI)
{
    const int CIH = CI / 2;
    const int n = CO * CIH * 27;
    if (i < n) {
        const int tap = i % 27;
        const int r   = i / 27;
        const int cp  = r % CIH;
        const int co  = r / CIH;
        const float* s = w + ((co * CI + 2 * cp) * 27 + tap);
        union { uint u; half2_t v; } c;
        c.v.x = (_Float16)s[0];
        c.v.y = (_Float16)s[27];
        h[i] = c.u;
    }
}

__global__ __launch_bounds__(256) void pack_weights(
    const float* w2, const float* w3, const float* w4, const float* w5,
    uint* h2, uint* h3, uint* h4, uint* h5)
{
    const int i = blockIdx.x * 256 + threadIdx.x;
    pack_one(i, w2, h2, 8, 4);
    pack_one(i, w3, h3, 16, 8);
    pack_one(i, w4, h4, 32, 16);
    pack_one(i, w5, h5, 64, 32);
}

// 6 parallel heads: [B,64] -> 32 -> 16 -> 4, lrelu each, then L2-normalize.
__global__ __launch_bounds__(256) void fc_heads(
    const float* __restrict__ feat,
    const float* __restrict__ W1, const float* __restrict__ b1,
    const float* __restrict__ W2, const float* __restrict__ b2,
    const float* __restrict__ W3, const float* __restrict__ b3,
    float* __restrict__ out, int B)
{
    const int tid = blockIdx.x * 256 + threadIdx.x;
    if (tid >= 6 * B) return;
    const int b = tid % B;
    const int h = tid / B;

    float f[64];
#pragma unroll
    for (int k = 0; k < 64; ++k) f[k] = feat[b * 64 + k];

    float h1[32];
#pragma unroll 1
    for (int j = 0; j < 32; ++j) {
        float s = b1[h * 32 + j];
#pragma unroll
        for (int k = 0; k < 64; ++k) s += f[k] * W1[(h * 64 + k) * 32 + j];
        h1[j] = lrelu(s);
    }
    float h2[16];
#pragma unroll 1
    for (int j = 0; j < 16; ++j) {
        float s = b2[h * 16 + j];
#pragma unroll
        for (int k = 0; k < 32; ++k) s += h1[k] * W2[(h * 32 + k) * 16 + j];
        h2[j] = lrelu(s);
    }
    float h3[4];
#pragma unroll
    for (int j = 0; j < 4; ++j) {
        float s = b3[h * 4 + j];
#pragma unroll
        for (int k = 0; k < 16; ++k) s += h2[k] * W3[(h * 16 + k) * 4 + j];
        h3[j] = lrelu(s);
    }
    const float n = sqrtf(h3[0] * h3[0] + h3[1] * h3[1] +
                          h3[2] * h3[2] + h3[3] * h3[3]);
    const float inv = 1.f / n;
#pragma unroll
    for (int q = 0; q < 4; ++q) out[(b * 6 + h) * 4 + q] = h3[q] * inv;
}

extern "C" void kernel_launch(void* const* d_in, const int* in_sizes, int n_in,
                              void* d_out, int out_size, void* d_ws, size_t ws_size,
                              hipStream_t stream)
{
    const float* voxel = (const float*)d_in[0];
    const float* cw1 = (const float*)d_in[1];  const float* cb1 = (const float*)d_in[2];
    const float* cw2 = (const float*)d_in[3];  const float* cb2 = (const float*)d_in[4];
    const float* cw3 = (const float*)d_in[5];  const float* cb3 = (const float*)d_in[6];
    const float* cw4 = (const float*)d_in[7];  const float* cb4 = (const float*)d_in[8];
    const float* cw5 = (const float*)d_in[9];  const float* cb5 = (const float*)d_in[10];
    const float* W1  = (const float*)d_in[11]; const float* b1  = (const float*)d_in[12];
    const float* W2  = (const float*)d_in[13]; const float* b2  = (const float*)d_in[14];
    const float* W3  = (const float*)d_in[15]; const float* b3  = (const float*)d_in[16];
    float* out = (float*)d_out;

    const int B = 1024;
    // workspace (words): activations half2-packed, feat fp32, packed weights
    uint*  buf1h = (uint*)d_ws;                  // [1024][2][16^3]  8388608
    uint*  buf2h = buf1h + 8388608;              // [1024][4][8^3]   2097152
    uint*  buf3h = buf2h + 2097152;              // [1024][8][4^3]    524288
    uint*  buf4h = buf3h + 524288;               // [1024][16][2^3]   131072
    float* buf5  = (float*)(buf4h + 131072);     // [1024][64]         65536
    uint*  wh2   = (uint*)(buf5 + 65536);        // 8*2*27   = 432
    uint*  wh3   = wh2 + 432;                    // 16*4*27  = 1728
    uint*  wh4   = wh3 + 1728;                   // 32*8*27  = 6912
    uint*  wh5   = wh4 + 6912;                   // 64*16*27 = 27648

    // pack conv2..conv5 weights into ci-pair half2 (27648 max threads)
    pack_weights<<<108, 256, 0, stream>>>(cw2, cw3, cw4, cw5, wh2, wh3, wh4, wh5);

    // L1 (fp32 compute, round-3 structure): 1->4, 32^3->16^3. ZT=2,PZT=2,CPT=4
    conv_pool_f32h<1, 4, 32, 2, 2, 4, 1><<<1024 * 8, 256, 0, stream>>>(
        voxel, cw1, cb1, (half2_t*)buf1h, B);
    // L2: CIH=2, 16^3->8^3. ZT=2,PZT=2,CPT=4,BPB=2. LDS 38016B -> 4 blk/CU
    conv_pool_h2<2, 8, 16, 2, 2, 4, 2><<<512 * 4, 256, 0, stream>>>(
        (const half2_t*)buf1h, (const half2_t*)wh2, cb2, (half2_t*)buf2h, B);
    // L3: CIH=4, 8^3->4^3. ZT=4,PZT=1,CPT=4. LDS 22400B -> 7 blk/CU
    conv_pool_h2<4, 16, 8, 4, 1, 4, 1><<<1024, 256, 0, stream>>>(
        (const half2_t*)buf2h, (const half2_t*)wh3, cb3, (half2_t*)buf3h, B);
    // L4: CIH=8, 4^3->2^3. ZT=2,PZT=1,CPT=2,BPB=2. LDS 23040B -> 6 blk/CU
    conv_pool_h2<8, 32, 4, 2, 1, 2, 2><<<512, 256, 0, stream>>>(
        (const half2_t*)buf3h, (const half2_t*)wh4, cb4, (half2_t*)buf4h, B);
    // L5: CIH=16, 2^3->1 -> feat fp32 [B,64]
    conv_pool_l5_h2<<<256, 256, 0, stream>>>(
        (const half2_t*)buf4h, (const half2_t*)wh5, cb5, buf5, B);
    // FC heads
    fc_heads<<<24, 256, 0, stream>>>(buf5, W1, b1, W2, b2, W3, b3, out, B);
}

// Round 6
// 502.324 us; speedup vs baseline: 1.3254x; 1.1444x over previous
//
#include <hip/hip_runtime.h>
#include <math.h>

#define NEG_SLOPE 0.2f

typedef _Float16 half2_t __attribute__((ext_vector_type(2)));

__device__ __forceinline__ float lrelu(float x) {
    return fmaxf(x, NEG_SLOPE * x);
}

__device__ __forceinline__ float fdot2(half2_t a, half2_t b, float c) {
#if __has_builtin(__builtin_amdgcn_fdot2)
    return __builtin_amdgcn_fdot2(a, b, c, false);
#else
    return c + (float)a.x * (float)b.x + (float)a.y * (float)b.y;
#endif
}

__device__ __forceinline__ half2_t as_h2(uint u) {
    union { uint u; half2_t h; } c; c.u = u; return c.h;
}

constexpr int clog2(int n) { return (n <= 1) ? 0 : 1 + clog2(n / 2); }

// ---------------------------------------------------------------------------
// Layer 1 (fp32, CI=1): round-3 skeleton; region reads now aligned float2
// (ds_read_b64, conflict-free: 16 lanes x 2 words covers all 32 banks).
// ---------------------------------------------------------------------------
template<int CI, int CO, int S, int ZT, int PZT, int CPT, int BPB>
__global__ __launch_bounds__(256) void conv_pool_f32h(
    const float* __restrict__ in,   // [B, CI, S,S,S]
    const float* __restrict__ w,    // [CO, CI, 3,3,3]
    const float* __restrict__ bias, // [CO]
    half2_t* __restrict__ out,      // [B, CO/2, SP^3] co-pair packed
    int B)
{
    constexpr int SP    = S / 2;
    constexpr int ZD    = 2 * ZT + 2;
    constexpr int YS    = S + 2;
    constexpr int XOFF  = 5;                 // region base 2xp+4 -> even
    constexpr int XR    = S + 8;             // even
    constexpr int PLANE = YS * XR;           // even
    constexpr int NPAIR = BPB * CI * ZD;
    constexpr int LDS_N = NPAIR * PLANE;
    constexpr int NOG   = CO / CPT;
    constexpr int NZB   = ZT / PZT;
    constexpr int NPOS  = NZB * SP * SP;
    constexpr int NSLAB = SP / ZT;
    static_assert(BPB * NOG * NPOS == 256, "thread mapping must cover block");
    static_assert((LDS_N & 3) == 0, "float4 zero");
    static_assert((CPT & 1) == 0, "pack pairs");

    __shared__ __align__(16) float sm[LDS_N];

    const int t     = threadIdx.x;
    const int zslab = blockIdx.x & (NSLAB - 1);
    const int b0    = (blockIdx.x >> clog2(NSLAB)) * BPB;
    const int zp0   = zslab * ZT;
    const int gz0   = 2 * zp0 - 1;

    {   // Phase A: zero LDS
        float4* s4 = (float4*)sm;
        constexpr int N4 = LDS_N / 4;
#pragma unroll
        for (int i = 0; i < (N4 + 255) / 256; ++i) {
            const int k = t + i * 256;
            if (k < N4) s4[k] = make_float4(0.f, 0.f, 0.f, 0.f);
        }
    }
    __syncthreads();

    {   // Phase B: interior rows, float4 loads
        constexpr int CHUNKS = S / 4;
        constexpr int PJOBS  = S * CHUNKS;
        constexpr int PPI    = 256 / PJOBS;
        constexpr int FITER  = NPAIR / PPI;
        static_assert(FITER * PPI == NPAIR, "fill covers planes exactly");
        const int idx  = t & (PJOBS - 1);
        const int poff = t >> clog2(PJOBS);
        const int cc   = idx & (CHUNKS - 1);
        const int yy   = idx >> clog2(CHUNKS);
#pragma unroll
        for (int it = 0; it < FITER; ++it) {
            const int plane = it * PPI + poff;
            const int z     = plane % ZD;
            const int bci   = plane / ZD;
            const int gz    = gz0 + z;
            if ((unsigned)gz < (unsigned)S) {
                const float4 v = *(const float4*)&in[
                    ((long)(b0 * CI + bci) * S + gz) * (S * S) + yy * S + 4 * cc];
                float* sp = &sm[(plane * YS + (yy + 1)) * XR + XOFF + 4 * cc];
                sp[0] = v.x; sp[1] = v.y; sp[2] = v.z; sp[3] = v.w;
            }
        }
    }
    __syncthreads();

    const int pos = t & (NPOS - 1);
    const int og  = (t >> clog2(NPOS)) & (NOG - 1);
    const int bl  = t >> clog2(NPOS * NOG);
    const int xp  = pos & (SP - 1);
    const int yp  = (pos >> clog2(SP)) & (SP - 1);
    const int zb  = pos >> (2 * clog2(SP));

#pragma unroll
    for (int zi = 0; zi < PZT; ++zi) {
        const int zl = zb * PZT + zi;
        float acc[CPT][8];
#pragma unroll
        for (int oo = 0; oo < CPT; ++oo)
#pragma unroll
            for (int p = 0; p < 8; ++p) acc[oo][p] = 0.f;

#pragma unroll 1
        for (int ci = 0; ci < CI; ++ci) {
            const float* sp_ = &sm[((bl * CI + ci) * ZD + 2 * zl) * PLANE +
                                   (2 * yp) * XR + 2 * xp + (XOFF - 1)]; // even
            float v[4][4][4];
#pragma unroll
            for (int dz = 0; dz < 4; ++dz)
#pragma unroll
                for (int dy = 0; dy < 4; ++dy) {
                    const float2 q0 = *(const float2*)&sp_[dz * PLANE + dy * XR];
                    const float2 q1 = *(const float2*)&sp_[dz * PLANE + dy * XR + 2];
                    v[dz][dy][0] = q0.x; v[dz][dy][1] = q0.y;
                    v[dz][dy][2] = q1.x; v[dz][dy][3] = q1.y;
                }
#pragma unroll
            for (int oo = 0; oo < CPT; ++oo) {
                const float* wp = w + (long)((og * CPT + oo) * CI + ci) * 27;
#pragma unroll
                for (int kz = 0; kz < 3; ++kz)
#pragma unroll
                    for (int ky = 0; ky < 3; ++ky)
#pragma unroll
                        for (int kx = 0; kx < 3; ++kx) {
                            const float wv = wp[kz * 9 + ky * 3 + kx];
#pragma unroll
                            for (int pz = 0; pz < 2; ++pz)
#pragma unroll
                                for (int py = 0; py < 2; ++py)
#pragma unroll
                                    for (int px = 0; px < 2; ++px)
                                        acc[oo][pz * 4 + py * 2 + px] +=
                                            v[pz + kz][py + ky][px + kx] * wv;
                        }
            }
        }

#pragma unroll
        for (int oo = 0; oo < CPT; oo += 2) {
            const int o = og * CPT + oo;
            float m0 = acc[oo][0], m1 = acc[oo + 1][0];
#pragma unroll
            for (int p = 1; p < 8; ++p) {
                m0 = fmaxf(m0, acc[oo][p]);
                m1 = fmaxf(m1, acc[oo + 1][p]);
            }
            half2_t hv;
            hv.x = (_Float16)lrelu(m0 + bias[o]);
            hv.y = (_Float16)lrelu(m1 + bias[o + 1]);
            out[(long)((b0 + bl) * (CO / 2) + (o >> 1)) * (SP * SP * SP) +
                ((zp0 + zl) * SP + yp) * SP + xp] = hv;
        }
    }
}

// ---------------------------------------------------------------------------
// Layer 2: half2 ci-pair data + dot2; region reads now aligned uint2
// (XOFF=3 -> region base 2xp+2 even -> ds_read_b64, conflict-free).
// ---------------------------------------------------------------------------
template<int CIH, int CO, int S, int ZT, int PZT, int CPT, int BPB>
__global__ __launch_bounds__(256) void conv_pool_h2(
    const half2_t* __restrict__ in,  // [B, CIH, S,S,S]
    const uint*   __restrict__ wh,   // [CO, CIH, 27] packed pairs
    const float*  __restrict__ bias, // [CO]
    half2_t* __restrict__ out,       // [B, CO/2, SP^3]
    int B)
{
    constexpr int SP    = S / 2;
    constexpr int ZD    = 2 * ZT + 2;
    constexpr int YS    = S + 2;
    constexpr int XOFF  = 3;
    constexpr int XR    = S + 6;             // even
    constexpr int PLANE = YS * XR;           // even
    constexpr int NPAIR = BPB * CIH * ZD;
    constexpr int LDS_N = NPAIR * PLANE;
    constexpr int NOG   = CO / CPT;
    constexpr int NZB   = ZT / PZT;
    constexpr int NPOS  = NZB * SP * SP;
    constexpr int NSLAB = SP / ZT;
    static_assert(BPB * NOG * NPOS == 256, "thread mapping must cover block");
    static_assert((LDS_N & 3) == 0, "uint4 zero");
    static_assert((CPT & 1) == 0, "pack pairs");

    __shared__ __align__(16) uint sm[LDS_N];
    const uint* inu = (const uint*)in;

    const int t     = threadIdx.x;
    const int zslab = blockIdx.x & (NSLAB - 1);
    const int b0    = (blockIdx.x >> clog2(NSLAB)) * BPB;
    const int zp0   = zslab * ZT;
    const int gz0   = 2 * zp0 - 1;

    {   // Phase A: zero LDS
        uint4* s4 = (uint4*)sm;
        constexpr int N4 = LDS_N / 4;
#pragma unroll
        for (int i = 0; i < (N4 + 255) / 256; ++i) {
            const int k = t + i * 256;
            if (k < N4) s4[k] = make_uint4(0, 0, 0, 0);
        }
    }
    __syncthreads();

    {   // Phase B: interior rows, uint2 global loads, scalar LDS stores
        constexpr int CH    = S / 2;
        constexpr int PJOBS = S * CH;
        constexpr int ITERS = NPAIR * PJOBS / 256;
        static_assert(ITERS * 256 == NPAIR * PJOBS, "exact fill");
#pragma unroll
        for (int it = 0; it < ITERS; ++it) {
            const int i     = t + it * 256;
            const int idx   = i & (PJOBS - 1);
            const int plane = i >> clog2(PJOBS);
            const int cc    = idx & (CH - 1);
            const int yy    = idx >> clog2(CH);
            const int z     = plane % ZD;
            const int bci   = plane / ZD;
            const int gz    = gz0 + z;
            if ((unsigned)gz < (unsigned)S) {
                const uint2 v = *(const uint2*)&inu[
                    ((long)(b0 * CIH + bci) * S + gz) * (S * S) + yy * S + 2 * cc];
                uint* sp = &sm[(plane * YS + yy + 1) * XR + XOFF + 2 * cc];
                sp[0] = v.x; sp[1] = v.y;
            }
        }
    }
    __syncthreads();

    const int pos = t & (NPOS - 1);
    const int og  = (t >> clog2(NPOS)) & (NOG - 1);
    const int bl  = t >> clog2(NPOS * NOG);
    const int xp  = pos & (SP - 1);
    const int yp  = (pos >> clog2(SP)) & (SP - 1);
    const int zb  = pos >> (2 * clog2(SP));

#pragma unroll
    for (int zi = 0; zi < PZT; ++zi) {
        const int zl = zb * PZT + zi;
        float acc[CPT][8];
#pragma unroll
        for (int oo = 0; oo < CPT; ++oo)
#pragma unroll
            for (int p = 0; p < 8; ++p) acc[oo][p] = 0.f;

#pragma unroll 1
        for (int cp = 0; cp < CIH; ++cp) {
            const uint* sp_ = &sm[((bl * CIH + cp) * ZD + 2 * zl) * PLANE +
                                  (2 * yp) * XR + 2 * xp + (XOFF - 1)]; // even
            half2_t v[4][4][4];
#pragma unroll
            for (int dz = 0; dz < 4; ++dz)
#pragma unroll
                for (int dy = 0; dy < 4; ++dy) {
                    const uint2 q0 = *(const uint2*)&sp_[dz * PLANE + dy * XR];
                    const uint2 q1 = *(const uint2*)&sp_[dz * PLANE + dy * XR + 2];
                    v[dz][dy][0] = as_h2(q0.x); v[dz][dy][1] = as_h2(q0.y);
                    v[dz][dy][2] = as_h2(q1.x); v[dz][dy][3] = as_h2(q1.y);
                }
#pragma unroll
            for (int oo = 0; oo < CPT; ++oo) {
                const uint* wp = wh + (long)((og * CPT + oo) * CIH + cp) * 27;
#pragma unroll
                for (int kz = 0; kz < 3; ++kz)
#pragma unroll
                    for (int ky = 0; ky < 3; ++ky)
#pragma unroll
                        for (int kx = 0; kx < 3; ++kx) {
                            const half2_t wv = as_h2(wp[kz * 9 + ky * 3 + kx]);
#pragma unroll
                            for (int pz = 0; pz < 2; ++pz)
#pragma unroll
                                for (int py = 0; py < 2; ++py)
#pragma unroll
                                    for (int px = 0; px < 2; ++px)
                                        acc[oo][pz * 4 + py * 2 + px] =
                                            fdot2(v[pz + kz][py + ky][px + kx],
                                                  wv, acc[oo][pz * 4 + py * 2 + px]);
                        }
            }
        }

#pragma unroll
        for (int oo = 0; oo < CPT; oo += 2) {
            const int o = og * CPT + oo;
            float m0 = acc[oo][0], m1 = acc[oo + 1][0];
#pragma unroll
            for (int p = 1; p < 8; ++p) {
                m0 = fmaxf(m0, acc[oo][p]);
                m1 = fmaxf(m1, acc[oo + 1][p]);
            }
            half2_t hv;
            hv.x = (_Float16)lrelu(m0 + bias[o]);
            hv.y = (_Float16)lrelu(m1 + bias[o + 1]);
            out[(long)((b0 + bl) * (CO / 2) + (o >> 1)) * (SP * SP * SP) +
                ((zp0 + zl) * SP + yp) * SP + xp] = hv;
        }
    }
}

// ---------------------------------------------------------------------------
// Fused tail: L3 (8->16, 8^3->4^3) + L4 (16->32, 4^3->2^3) + L5 (32->64,
// 2^3->1) + 6 FC heads + normalize. One block = 2 batches, all staging in
// LDS (62 KB -> exactly 2 blocks/CU). Activations between stages stored
// ci-interleaved (spatial*NC + ci) so the next stage reads aligned half2.
// ---------------------------------------------------------------------------
__global__ __launch_bounds__(256) void tail_fused(
    const uint*  __restrict__ in,   // buf2h [B][4][8^3] half2 words
    const uint*  __restrict__ wh3,  // [16][4][27]
    const uint*  __restrict__ wh4,  // [32][8][27]
    const uint*  __restrict__ wh5,  // [64][16][27]
    const float* __restrict__ cb3, const float* __restrict__ cb4,
    const float* __restrict__ cb5,
    const float* __restrict__ W1, const float* __restrict__ fb1,
    const float* __restrict__ W2, const float* __restrict__ fb2,
    const float* __restrict__ W3, const float* __restrict__ fb3,
    float* __restrict__ out)        // [B,6,4]
{
    // LDS word offsets
    constexpr int S3IN   = 0;      // [bl2][cp4][z10][y10][x12]      9600 w
    constexpr int S3OUTW = 9600;   // halves [bl2][z6][y6][x6][co16] 3456 w
    constexpr int S4OUTW = 13056;  // words  [bl2][z4][y4][x4][ch16] 2048 w
    constexpr int FEATW  = 15104;  // float  [bl2][64]                128 w
    constexpr int H1W    = 15232;  // float  [12][32]                 384 w
    constexpr int H2W    = 15616;  // float  [12][16]                 192 w
    constexpr int H3W    = 15808;  // float  [12][4]                   48 w
    constexpr int LDS_N  = 15872;  // padded, 63488 B

    __shared__ __align__(16) uint sm[LDS_N];
    float* smf = (float*)sm;
    _Float16* s3h = (_Float16*)(sm + S3OUTW);

    const int t  = threadIdx.x;
    const int b0 = blockIdx.x * 2;

    // ---- zero all LDS ----
    {
        uint4* s4 = (uint4*)sm;
#pragma unroll
        for (int i = 0; i < 16; ++i) {
            const int k = t + i * 256;
            if (k < LDS_N / 4) s4[k] = make_uint4(0, 0, 0, 0);
        }
    }
    __syncthreads();

    // ---- fill L3 input interior: 2bl x 4cp x 8z x 8y x 4 uint2 = 2048 jobs
    {
#pragma unroll
        for (int it = 0; it < 8; ++it) {
            const int i   = t + it * 256;
            const int xc  = i & 3;
            const int yy  = (i >> 2) & 7;
            const int zz  = (i >> 5) & 7;
            const int bcp = i >> 8;           // bl*4 + cp
            const uint2 v = *(const uint2*)&in[
                ((long)(b0 + (bcp >> 2)) * 4 + (bcp & 3)) * 512 +
                (zz * 8 + yy) * 8 + 2 * xc];
            uint* sp = &sm[S3IN + (bcp * 10 + zz + 1) * 120 + (yy + 1) * 12 +
                           3 + 2 * xc];
            sp[0] = v.x; sp[1] = v.y;
        }
    }
    __syncthreads();

    // ---- L3: 256 threads = bl2 x co16 x (zp4 x yh2); 8 outputs/thread ----
    {
        const int pt = t & 7;
        const int zp = pt >> 1;
        const int yh = pt & 1;
        const int co = (t >> 3) & 15;
        const int bl = t >> 7;
#pragma unroll
        for (int yy = 0; yy < 2; ++yy) {
            const int yp = 2 * yh + yy;
#pragma unroll
            for (int xp = 0; xp < 4; ++xp) {
                float acc[8];
#pragma unroll
                for (int p = 0; p < 8; ++p) acc[p] = 0.f;
#pragma unroll
                for (int cp = 0; cp < 4; ++cp) {
                    const uint* base = &sm[S3IN + ((bl * 4 + cp) * 10 + 2 * zp) * 120 +
                                           (2 * yp) * 12 + 2 * xp + 2]; // even
                    half2_t v[4][4][4];
#pragma unroll
                    for (int dz = 0; dz < 4; ++dz)
#pragma unroll
                        for (int dy = 0; dy < 4; ++dy) {
                            const uint2 q0 = *(const uint2*)&base[dz * 120 + dy * 12];
                            const uint2 q1 = *(const uint2*)&base[dz * 120 + dy * 12 + 2];
                            v[dz][dy][0] = as_h2(q0.x); v[dz][dy][1] = as_h2(q0.y);
                            v[dz][dy][2] = as_h2(q1.x); v[dz][dy][3] = as_h2(q1.y);
                        }
                    const uint* wp = &wh3[(co * 4 + cp) * 27];
#pragma unroll
                    for (int kz = 0; kz < 3; ++kz)
#pragma unroll
                        for (int ky = 0; ky < 3; ++ky)
#pragma unroll
                            for (int kx = 0; kx < 3; ++kx) {
                                const half2_t wv = as_h2(wp[kz * 9 + ky * 3 + kx]);
#pragma unroll
                                for (int pz = 0; pz < 2; ++pz)
#pragma unroll
                                    for (int py = 0; py < 2; ++py)
#pragma unroll
                                        for (int px = 0; px < 2; ++px)
                                            acc[pz * 4 + py * 2 + px] =
                                                fdot2(v[pz + kz][py + ky][px + kx],
                                                      wv, acc[pz * 4 + py * 2 + px]);
                            }
                }
                float m = acc[0];
#pragma unroll
                for (int p = 1; p < 8; ++p) m = fmaxf(m, acc[p]);
                s3h[((((bl * 6 + zp + 1) * 6 + yp + 1) * 6 + xp + 1) << 4) + co] =
                    (_Float16)lrelu(m + cb3[co]);
            }
        }
    }
    __syncthreads();

    // ---- L4: 256 threads = bl2 x cp16(co-pair) x pos8; 1 output-pair ----
    {
        const int xp = t & 1;
        const int yp = (t >> 1) & 1;
        const int zp = (t >> 2) & 1;
        const int cp = (t >> 3) & 15;
        const int bl = t >> 7;
        float a0[8], a1[8];
#pragma unroll
        for (int p = 0; p < 8; ++p) { a0[p] = 0.f; a1[p] = 0.f; }
#pragma unroll 1
        for (int c = 0; c < 8; ++c) {
            half2_t v[4][4][4];
#pragma unroll
            for (int dz = 0; dz < 4; ++dz)
#pragma unroll
                for (int dy = 0; dy < 4; ++dy)
#pragma unroll
                    for (int dx = 0; dx < 4; ++dx)
                        v[dz][dy][dx] = as_h2(sm[S3OUTW +
                            ((((bl * 6 + 2 * zp + dz) * 6 + 2 * yp + dy) * 6 +
                              (2 * xp + dx)) << 3) + c]);
            const uint* wp0 = &wh4[((2 * cp) * 8 + c) * 27];
            const uint* wp1 = &wh4[((2 * cp + 1) * 8 + c) * 27];
#pragma unroll
            for (int kz = 0; kz < 3; ++kz)
#pragma unroll
                for (int ky = 0; ky < 3; ++ky)
#pragma unroll
                    for (int kx = 0; kx < 3; ++kx) {
                        const half2_t w0 = as_h2(wp0[kz * 9 + ky * 3 + kx]);
                        const half2_t w1 = as_h2(wp1[kz * 9 + ky * 3 + kx]);
#pragma unroll
                        for (int pz = 0; pz < 2; ++pz)
#pragma unroll
                            for (int py = 0; py < 2; ++py)
#pragma unroll
                                for (int px = 0; px < 2; ++px) {
                                    const half2_t vv = v[pz + kz][py + ky][px + kx];
                                    const int ai = pz * 4 + py * 2 + px;
                                    a0[ai] = fdot2(vv, w0, a0[ai]);
                                    a1[ai] = fdot2(vv, w1, a1[ai]);
                                }
                    }
        }
        float m0 = a0[0], m1 = a1[0];
#pragma unroll
        for (int p = 1; p < 8; ++p) { m0 = fmaxf(m0, a0[p]); m1 = fmaxf(m1, a1[p]); }
        half2_t hv;
        hv.x = (_Float16)lrelu(m0 + cb4[2 * cp]);
        hv.y = (_Float16)lrelu(m1 + cb4[2 * cp + 1]);
        union { half2_t h; uint u; } cvt; cvt.h = hv;
        sm[S4OUTW + ((((bl * 4 + zp + 1) * 4 + yp + 1) * 4 + (xp + 1)) << 4) + cp] = cvt.u;
    }
    __syncthreads();

    // ---- L5: 128 threads = bl2 x co64 -> feat[bl][64] fp32 ----
    if (t < 128) {
        const int co = t & 63;
        const int bl = t >> 6;
        float acc[8];
#pragma unroll
        for (int p = 0; p < 8; ++p) acc[p] = 0.f;
#pragma unroll 1
        for (int c = 0; c < 16; ++c) {
            half2_t v[4][4][4];
#pragma unroll
            for (int dz = 0; dz < 4; ++dz)
#pragma unroll
                for (int dy = 0; dy < 4; ++dy)
#pragma unroll
                    for (int dx = 0; dx < 4; ++dx)
                        v[dz][dy][dx] = as_h2(sm[S4OUTW +
                            ((((bl * 4 + dz) * 4 + dy) * 4 + dx) << 4) + c]);
            const uint* wp = &wh5[(co * 16 + c) * 27];
#pragma unroll
            for (int kz = 0; kz < 3; ++kz)
#pragma unroll
                for (int ky = 0; ky < 3; ++ky)
#pragma unroll
                    for (int kx = 0; kx < 3; ++kx) {
                        const half2_t wv = as_h2(wp[kz * 9 + ky * 3 + kx]);
#pragma unroll
                        for (int pz = 0; pz < 2; ++pz)
#pragma unroll
                            for (int py = 0; py < 2; ++py)
#pragma unroll
                                for (int px = 0; px < 2; ++px)
                                    acc[pz * 4 + py * 2 + px] =
                                        fdot2(v[pz + kz][py + ky][px + kx], wv,
                                              acc[pz * 4 + py * 2 + px]);
                    }
        }
        float m = acc[0];
#pragma unroll
        for (int p = 1; p < 8; ++p) m = fmaxf(m, acc[p]);
        smf[FEATW + bl * 64 + co] = lrelu(m + cb5[co]);
    }
    __syncthreads();

    // ---- FC1: 384 jobs = (bl2 x h6) x j32 ----
#pragma unroll
    for (int jj = 0; jj < 2; ++jj) {
        const int job = t + jj * 256;
        if (job < 384) {
            const int j = job & 31;
            const int g = job >> 5;          // bl*6 + h
            const int h = g % 6;
            const int bl = g / 6;
            float s = fb1[h * 32 + j];
#pragma unroll
            for (int k = 0; k < 64; ++k)
                s += smf[FEATW + bl * 64 + k] * W1[(h * 64 + k) * 32 + j];
            smf[H1W + g * 32 + j] = lrelu(s);
        }
    }
    __syncthreads();

    // ---- FC2: 192 jobs ----
    if (t < 192) {
        const int j = t & 15;
        const int g = t >> 4;
        const int h = g % 6;
        float s = fb2[h * 16 + j];
#pragma unroll
        for (int k = 0; k < 32; ++k)
            s += smf[H1W + g * 32 + k] * W2[(h * 32 + k) * 16 + j];
        smf[H2W + g * 16 + j] = lrelu(s);
    }
    __syncthreads();

    // ---- FC3: 48 jobs ----
    if (t < 48) {
        const int j = t & 3;
        const int g = t >> 2;
        const int h = g % 6;
        float s = fb3[h * 4 + j];
#pragma unroll
        for (int k = 0; k < 16; ++k)
            s += smf[H2W + g * 16 + k] * W3[(h * 16 + k) * 4 + j];
        smf[H3W + g * 4 + j] = lrelu(s);
    }
    __syncthreads();

    // ---- normalize + store: 48 jobs ----
    if (t < 48) {
        const int q = t & 3;
        const int g = t >> 2;
        const int h = g % 6;
        const int bl = g / 6;
        const float x0 = smf[H3W + g * 4 + 0];
        const float x1 = smf[H3W + g * 4 + 1];
        const float x2 = smf[H3W + g * 4 + 2];
        const float x3 = smf[H3W + g * 4 + 3];
        const float inv = 1.f / sqrtf(x0 * x0 + x1 * x1 + x2 * x2 + x3 * x3);
        out[((b0 + bl) * 6 + h) * 4 + q] = smf[H3W + g * 4 + q] * inv;
    }
}

// ---------------------------------------------------------------------------
// Weight pre-pack: fp32 [CO][CI][27] -> half2 [CO][CI/2][27] (pairs over ci).
// ---------------------------------------------------------------------------
__device__ __forceinline__ void pack_one(int i, const float* w, uint* h,
                                         int CO, int CI)
{
    const int CIH = CI / 2;
    const int n = CO * CIH * 27;
    if (i < n) {
        const int tap = i % 27;
        const int r   = i / 27;
        const int cp  = r % CIH;
        const int co  = r / CIH;
        const float* s = w + ((co * CI + 2 * cp) * 27 + tap);
        union { uint u; half2_t v; } c;
        c.v.x = (_Float16)s[0];
        c.v.y = (_Float16)s[27];
        h[i] = c.u;
    }
}

__global__ __launch_bounds__(256) void pack_weights(
    const float* w2, const float* w3, const float* w4, const float* w5,
    uint* h2, uint* h3, uint* h4, uint* h5)
{
    const int i = blockIdx.x * 256 + threadIdx.x;
    pack_one(i, w2, h2, 8, 4);
    pack_one(i, w3, h3, 16, 8);
    pack_one(i, w4, h4, 32, 16);
    pack_one(i, w5, h5, 64, 32);
}

extern "C" void kernel_launch(void* const* d_in, const int* in_sizes, int n_in,
                              void* d_out, int out_size, void* d_ws, size_t ws_size,
                              hipStream_t stream)
{
    const float* voxel = (const float*)d_in[0];
    const float* cw1 = (const float*)d_in[1];  const float* cb1 = (const float*)d_in[2];
    const float* cw2 = (const float*)d_in[3];  const float* cb2 = (const float*)d_in[4];
    const float* cw3 = (const float*)d_in[5];  const float* cb3 = (const float*)d_in[6];
    const float* cw4 = (const float*)d_in[7];  const float* cb4 = (const float*)d_in[8];
    const float* cw5 = (const float*)d_in[9];  const float* cb5 = (const float*)d_in[10];
    const float* W1  = (const float*)d_in[11]; const float* b1  = (const float*)d_in[12];
    const float* W2  = (const float*)d_in[13]; const float* b2  = (const float*)d_in[14];
    const float* W3  = (const float*)d_in[15]; const float* b3  = (const float*)d_in[16];
    float* out = (float*)d_out;

    const int B = 1024;
    uint* buf1h = (uint*)d_ws;                 // [1024][2][16^3]  8388608 w
    uint* buf2h = buf1h + 8388608;             // [1024][4][8^3]   2097152 w
    uint* wh2   = buf2h + 2097152;             // 432
    uint* wh3   = wh2 + 432;                   // 1728
    uint* wh4   = wh3 + 1728;                  // 6912
    uint* wh5   = wh4 + 6912;                  // 27648

    pack_weights<<<108, 256, 0, stream>>>(cw2, cw3, cw4, cw5, wh2, wh3, wh4, wh5);

    // L1: 1->4, 32^3->16^3 (fp32 compute, b64 LDS reads)
    conv_pool_f32h<1, 4, 32, 2, 2, 4, 1><<<1024 * 8, 256, 0, stream>>>(
        voxel, cw1, cb1, (half2_t*)buf1h, B);
    // L2: CIH=2, 16^3->8^3 (dot2, b64 LDS reads)
    conv_pool_h2<2, 8, 16, 2, 2, 4, 2><<<512 * 4, 256, 0, stream>>>(
        (const half2_t*)buf1h, wh2, cb2, (half2_t*)buf2h, B);
    // L3+L4+L5+FC fused: 2 batches/block
    tail_fused<<<512, 256, 0, stream>>>(
        buf2h, wh3, wh4, wh5, cb3, cb4, cb5,
        W1, b1, W2, b2, W3, b3, out);
}

// Round 7
// 455.595 us; speedup vs baseline: 1.4613x; 1.1026x over previous
//
#include <hip/hip_runtime.h>
#include <math.h>

#define NEG_SLOPE 0.2f

typedef _Float16 half2_t __attribute__((ext_vector_type(2)));

__device__ __forceinline__ float lrelu(float x) {
    return fmaxf(x, NEG_SLOPE * x);
}

__device__ __forceinline__ float fdot2(half2_t a, half2_t b, float c) {
#if __has_builtin(__builtin_amdgcn_fdot2)
    return __builtin_amdgcn_fdot2(a, b, c, false);
#else
    return c + (float)a.x * (float)b.x + (float)a.y * (float)b.y;
#endif
}

__device__ __forceinline__ half2_t as_h2(uint u) {
    union { uint u; half2_t h; } c; c.u = u; return c.h;
}

constexpr int clog2(int n) { return (n <= 1) ? 0 : 1 + clog2(n / 2); }

// ---------------------------------------------------------------------------
// Layer 1 (fp32, CI=1). launch_bounds(256,4): 128 VGPRs so v[64]+acc[32]
// stay in VGPRs (80-VGPR build spilled to AGPRs -> accvgpr-move VALU tax).
// ---------------------------------------------------------------------------
template<int CI, int CO, int S, int ZT, int PZT, int CPT, int BPB>
__global__ __launch_bounds__(256, 4) void conv_pool_f32h(
    const float* __restrict__ in,   // [B, CI, S,S,S]
    const float* __restrict__ w,    // [CO, CI, 3,3,3]
    const float* __restrict__ bias, // [CO]
    half2_t* __restrict__ out,      // [B, CO/2, SP^3] co-pair packed
    int B)
{
    constexpr int SP    = S / 2;
    constexpr int ZD    = 2 * ZT + 2;
    constexpr int YS    = S + 2;
    constexpr int XOFF  = 5;
    constexpr int XR    = S + 8;
    constexpr int PLANE = YS * XR;
    constexpr int NPAIR = BPB * CI * ZD;
    constexpr int LDS_N = NPAIR * PLANE;
    constexpr int NOG   = CO / CPT;
    constexpr int NZB   = ZT / PZT;
    constexpr int NPOS  = NZB * SP * SP;
    constexpr int NSLAB = SP / ZT;
    static_assert(BPB * NOG * NPOS == 256, "thread mapping must cover block");
    static_assert((LDS_N & 3) == 0, "float4 zero");
    static_assert((CPT & 1) == 0, "pack pairs");

    __shared__ __align__(16) float sm[LDS_N];

    const int t     = threadIdx.x;
    const int zslab = blockIdx.x & (NSLAB - 1);
    const int b0    = (blockIdx.x >> clog2(NSLAB)) * BPB;
    const int zp0   = zslab * ZT;
    const int gz0   = 2 * zp0 - 1;

    {   // Phase A: zero LDS
        float4* s4 = (float4*)sm;
        constexpr int N4 = LDS_N / 4;
#pragma unroll
        for (int i = 0; i < (N4 + 255) / 256; ++i) {
            const int k = t + i * 256;
            if (k < N4) s4[k] = make_float4(0.f, 0.f, 0.f, 0.f);
        }
    }
    __syncthreads();

    {   // Phase B: interior rows, float4 loads
        constexpr int CHUNKS = S / 4;
        constexpr int PJOBS  = S * CHUNKS;
        constexpr int PPI    = 256 / PJOBS;
        constexpr int FITER  = NPAIR / PPI;
        static_assert(FITER * PPI == NPAIR, "fill covers planes exactly");
        const int idx  = t & (PJOBS - 1);
        const int poff = t >> clog2(PJOBS);
        const int cc   = idx & (CHUNKS - 1);
        const int yy   = idx >> clog2(CHUNKS);
#pragma unroll
        for (int it = 0; it < FITER; ++it) {
            const int plane = it * PPI + poff;
            const int z     = plane % ZD;
            const int bci   = plane / ZD;
            const int gz    = gz0 + z;
            if ((unsigned)gz < (unsigned)S) {
                const float4 v = *(const float4*)&in[
                    ((long)(b0 * CI + bci) * S + gz) * (S * S) + yy * S + 4 * cc];
                float* sp = &sm[(plane * YS + (yy + 1)) * XR + XOFF + 4 * cc];
                sp[0] = v.x; sp[1] = v.y; sp[2] = v.z; sp[3] = v.w;
            }
        }
    }
    __syncthreads();

    const int pos = t & (NPOS - 1);
    const int og  = (t >> clog2(NPOS)) & (NOG - 1);
    const int bl  = t >> clog2(NPOS * NOG);
    const int xp  = pos & (SP - 1);
    const int yp  = (pos >> clog2(SP)) & (SP - 1);
    const int zb  = pos >> (2 * clog2(SP));

#pragma unroll
    for (int zi = 0; zi < PZT; ++zi) {
        const int zl = zb * PZT + zi;
        float acc[CPT][8];
#pragma unroll
        for (int oo = 0; oo < CPT; ++oo)
#pragma unroll
            for (int p = 0; p < 8; ++p) acc[oo][p] = 0.f;

#pragma unroll 1
        for (int ci = 0; ci < CI; ++ci) {
            const float* sp_ = &sm[((bl * CI + ci) * ZD + 2 * zl) * PLANE +
                                   (2 * yp) * XR + 2 * xp + (XOFF - 1)]; // even
            float v[4][4][4];
#pragma unroll
            for (int dz = 0; dz < 4; ++dz)
#pragma unroll
                for (int dy = 0; dy < 4; ++dy) {
                    const float2 q0 = *(const float2*)&sp_[dz * PLANE + dy * XR];
                    const float2 q1 = *(const float2*)&sp_[dz * PLANE + dy * XR + 2];
                    v[dz][dy][0] = q0.x; v[dz][dy][1] = q0.y;
                    v[dz][dy][2] = q1.x; v[dz][dy][3] = q1.y;
                }
#pragma unroll
            for (int oo = 0; oo < CPT; ++oo) {
                const float* wp = w + (long)((og * CPT + oo) * CI + ci) * 27;
#pragma unroll
                for (int kz = 0; kz < 3; ++kz)
#pragma unroll
                    for (int ky = 0; ky < 3; ++ky)
#pragma unroll
                        for (int kx = 0; kx < 3; ++kx) {
                            const float wv = wp[kz * 9 + ky * 3 + kx];
#pragma unroll
                            for (int pz = 0; pz < 2; ++pz)
#pragma unroll
                                for (int py = 0; py < 2; ++py)
#pragma unroll
                                    for (int px = 0; px < 2; ++px)
                                        acc[oo][pz * 4 + py * 2 + px] +=
                                            v[pz + kz][py + ky][px + kx] * wv;
                        }
            }
        }

#pragma unroll
        for (int oo = 0; oo < CPT; oo += 2) {
            const int o = og * CPT + oo;
            float m0 = acc[oo][0], m1 = acc[oo + 1][0];
#pragma unroll
            for (int p = 1; p < 8; ++p) {
                m0 = fmaxf(m0, acc[oo][p]);
                m1 = fmaxf(m1, acc[oo + 1][p]);
            }
            half2_t hv;
            hv.x = (_Float16)lrelu(m0 + bias[o]);
            hv.y = (_Float16)lrelu(m1 + bias[o + 1]);
            out[(long)((b0 + bl) * (CO / 2) + (o >> 1)) * (SP * SP * SP) +
                ((zp0 + zl) * SP + yp) * SP + xp] = hv;
        }
    }
}

// ---------------------------------------------------------------------------
// Layer 2: half2 ci-pair data + dot2.
// ---------------------------------------------------------------------------
template<int CIH, int CO, int S, int ZT, int PZT, int CPT, int BPB>
__global__ __launch_bounds__(256, 4) void conv_pool_h2(
    const half2_t* __restrict__ in,  // [B, CIH, S,S,S]
    const uint*   __restrict__ wh,   // [CO, CIH, 27] packed pairs
    const float*  __restrict__ bias, // [CO]
    half2_t* __restrict__ out,       // [B, CO/2, SP^3]
    int B)
{
    constexpr int SP    = S / 2;
    constexpr int ZD    = 2 * ZT + 2;
    constexpr int YS    = S + 2;
    constexpr int XOFF  = 3;
    constexpr int XR    = S + 6;
    constexpr int PLANE = YS * XR;
    constexpr int NPAIR = BPB * CIH * ZD;
    constexpr int LDS_N = NPAIR * PLANE;
    constexpr int NOG   = CO / CPT;
    constexpr int NZB   = ZT / PZT;
    constexpr int NPOS  = NZB * SP * SP;
    constexpr int NSLAB = SP / ZT;
    static_assert(BPB * NOG * NPOS == 256, "thread mapping must cover block");
    static_assert((LDS_N & 3) == 0, "uint4 zero");
    static_assert((CPT & 1) == 0, "pack pairs");

    __shared__ __align__(16) uint sm[LDS_N];
    const uint* inu = (const uint*)in;

    const int t     = threadIdx.x;
    const int zslab = blockIdx.x & (NSLAB - 1);
    const int b0    = (blockIdx.x >> clog2(NSLAB)) * BPB;
    const int zp0   = zslab * ZT;
    const int gz0   = 2 * zp0 - 1;

    {   // Phase A: zero LDS
        uint4* s4 = (uint4*)sm;
        constexpr int N4 = LDS_N / 4;
#pragma unroll
        for (int i = 0; i < (N4 + 255) / 256; ++i) {
            const int k = t + i * 256;
            if (k < N4) s4[k] = make_uint4(0, 0, 0, 0);
        }
    }
    __syncthreads();

    {   // Phase B: interior rows, uint2 global loads
        constexpr int CH    = S / 2;
        constexpr int PJOBS = S * CH;
        constexpr int ITERS = NPAIR * PJOBS / 256;
        static_assert(ITERS * 256 == NPAIR * PJOBS, "exact fill");
#pragma unroll
        for (int it = 0; it < ITERS; ++it) {
            const int i     = t + it * 256;
            const int idx   = i & (PJOBS - 1);
            const int plane = i >> clog2(PJOBS);
            const int cc    = idx & (CH - 1);
            const int yy    = idx >> clog2(CH);
            const int z     = plane % ZD;
            const int bci   = plane / ZD;
            const int gz    = gz0 + z;
            if ((unsigned)gz < (unsigned)S) {
                const uint2 v = *(const uint2*)&inu[
                    ((long)(b0 * CIH + bci) * S + gz) * (S * S) + yy * S + 2 * cc];
                uint* sp = &sm[(plane * YS + yy + 1) * XR + XOFF + 2 * cc];
                sp[0] = v.x; sp[1] = v.y;
            }
        }
    }
    __syncthreads();

    const int pos = t & (NPOS - 1);
    const int og  = (t >> clog2(NPOS)) & (NOG - 1);
    const int bl  = t >> clog2(NPOS * NOG);
    const int xp  = pos & (SP - 1);
    const int yp  = (pos >> clog2(SP)) & (SP - 1);
    const int zb  = pos >> (2 * clog2(SP));

#pragma unroll
    for (int zi = 0; zi < PZT; ++zi) {
        const int zl = zb * PZT + zi;
        float acc[CPT][8];
#pragma unroll
        for (int oo = 0; oo < CPT; ++oo)
#pragma unroll
            for (int p = 0; p < 8; ++p) acc[oo][p] = 0.f;

#pragma unroll 1
        for (int cp = 0; cp < CIH; ++cp) {
            const uint* sp_ = &sm[((bl * CIH + cp) * ZD + 2 * zl) * PLANE +
                                  (2 * yp) * XR + 2 * xp + (XOFF - 1)]; // even
            half2_t v[4][4][4];
#pragma unroll
            for (int dz = 0; dz < 4; ++dz)
#pragma unroll
                for (int dy = 0; dy < 4; ++dy) {
                    const uint2 q0 = *(const uint2*)&sp_[dz * PLANE + dy * XR];
                    const uint2 q1 = *(const uint2*)&sp_[dz * PLANE + dy * XR + 2];
                    v[dz][dy][0] = as_h2(q0.x); v[dz][dy][1] = as_h2(q0.y);
                    v[dz][dy][2] = as_h2(q1.x); v[dz][dy][3] = as_h2(q1.y);
                }
#pragma unroll
            for (int oo = 0; oo < CPT; ++oo) {
                const uint* wp = wh + (long)((og * CPT + oo) * CIH + cp) * 27;
#pragma unroll
                for (int kz = 0; kz < 3; ++kz)
#pragma unroll
                    for (int ky = 0; ky < 3; ++ky)
#pragma unroll
                        for (int kx = 0; kx < 3; ++kx) {
                            const half2_t wv = as_h2(wp[kz * 9 + ky * 3 + kx]);
#pragma unroll
                            for (int pz = 0; pz < 2; ++pz)
#pragma unroll
                                for (int py = 0; py < 2; ++py)
#pragma unroll
                                    for (int px = 0; px < 2; ++px)
                                        acc[oo][pz * 4 + py * 2 + px] =
                                            fdot2(v[pz + kz][py + ky][px + kx],
                                                  wv, acc[oo][pz * 4 + py * 2 + px]);
                        }
            }
        }

#pragma unroll
        for (int oo = 0; oo < CPT; oo += 2) {
            const int o = og * CPT + oo;
            float m0 = acc[oo][0], m1 = acc[oo + 1][0];
#pragma unroll
            for (int p = 1; p < 8; ++p) {
                m0 = fmaxf(m0, acc[oo][p]);
                m1 = fmaxf(m1, acc[oo + 1][p]);
            }
            half2_t hv;
            hv.x = (_Float16)lrelu(m0 + bias[o]);
            hv.y = (_Float16)lrelu(m1 + bias[o + 1]);
            out[(long)((b0 + bl) * (CO / 2) + (o >> 1)) * (SP * SP * SP) +
                ((zp0 + zl) * SP + yp) * SP + xp] = hv;
        }
    }
}

// ---------------------------------------------------------------------------
// Fused tail v2: 1 batch/block (1024 blocks, 31.7 KB LDS, 4 blk/CU).
// L3: 64 pos x 4 co-groups, co wave-uniform (readfirstlane -> s_load weights),
//     each v-region read feeds 4 co.
// L4: 8 pos x 32 co (v reads wave-broadcast).
// L5: 64 co x 4 ci-groups + LDS partial reduce (stride 9, conflict-free).
// ---------------------------------------------------------------------------
__global__ __launch_bounds__(256, 4) void tail_fused2(
    const uint*  __restrict__ in,   // buf2h [B][4][8^3] half2 words
    const uint*  __restrict__ wh3,  // [16][4][27]
    const uint*  __restrict__ wh4,  // [32][8][27]
    const uint*  __restrict__ wh5,  // [64][16][27]
    const float* __restrict__ cb3, const float* __restrict__ cb4,
    const float* __restrict__ cb5,
    const float* __restrict__ W1, const float* __restrict__ fb1,
    const float* __restrict__ W2, const float* __restrict__ fb2,
    const float* __restrict__ W3, const float* __restrict__ fb3,
    float* __restrict__ out)        // [B,6,4]
{
    // LDS word offsets (one batch)
    constexpr int S3IN  = 0;      // [cp4][z10][y10][x12]              4800 w
    constexpr int S3OUT = 4800;   // halves [z6][y6][x6][c16]          1728 w
    constexpr int S4OUT = 6528;   // words  [z4][y4][x4][c16]          1024 w
    constexpr int FEAT  = 7552;   // f32 [64]
    constexpr int H1O   = 7616;   // f32 [6][32]
    constexpr int H2O   = 7808;   // f32 [6][16]
    constexpr int H3O   = 7904;   // f32 [6][4]
    constexpr int LDS_N = 7936;   // 31744 B
    // L5 partials reuse S3IN space after L3: f32 [cq4][co64][9]

    __shared__ __align__(16) uint sm[LDS_N];
    float* smf = (float*)sm;
    _Float16* s3h = (_Float16*)(sm + S3OUT);
    _Float16* s4h = (_Float16*)(sm + S4OUT);

    const int t = threadIdx.x;
    const int b = blockIdx.x;

    // ---- zero all LDS ----
    {
        uint4* s4 = (uint4*)sm;
#pragma unroll
        for (int i = 0; i < 8; ++i) {
            const int k = t + i * 256;
            if (k < LDS_N / 4) s4[k] = make_uint4(0, 0, 0, 0);
        }
    }
    __syncthreads();

    // ---- fill L3 input interior: 4cp x 8z x 8y x 4 uint2 = 1024 jobs ----
#pragma unroll
    for (int it = 0; it < 4; ++it) {
        const int i  = t + it * 256;
        const int xc = i & 3;
        const int yy = (i >> 2) & 7;
        const int zz = (i >> 5) & 7;
        const int cp = i >> 8;
        const uint2 v = *(const uint2*)&in[
            ((long)b * 4 + cp) * 512 + (zz * 8 + yy) * 8 + 2 * xc];
        uint* sp = &sm[S3IN + cp * 1200 + (zz + 1) * 120 + (yy + 1) * 12 +
                       3 + 2 * xc];
        sp[0] = v.x; sp[1] = v.y;
    }
    __syncthreads();

    // ---- L3: pos64 x cog4 (wave-uniform), 4 co per thread ----
    {
        const int pos = t & 63;
        const int cog = __builtin_amdgcn_readfirstlane(t >> 6);  // wave-uniform
        const int xp = pos & 3;
        const int yp = (pos >> 2) & 3;
        const int zp = pos >> 4;

        float acc[4][8];
#pragma unroll
        for (int oo = 0; oo < 4; ++oo)
#pragma unroll
            for (int p = 0; p < 8; ++p) acc[oo][p] = 0.f;

#pragma unroll 1
        for (int cp = 0; cp < 4; ++cp) {
            const uint* base = &sm[S3IN + cp * 1200 + 2 * zp * 120 +
                                   2 * yp * 12 + 2 * xp + 2]; // even
            half2_t v[4][4][4];
#pragma unroll
            for (int dz = 0; dz < 4; ++dz)
#pragma unroll
                for (int dy = 0; dy < 4; ++dy) {
                    const uint2 q0 = *(const uint2*)&base[dz * 120 + dy * 12];
                    const uint2 q1 = *(const uint2*)&base[dz * 120 + dy * 12 + 2];
                    v[dz][dy][0] = as_h2(q0.x); v[dz][dy][1] = as_h2(q0.y);
                    v[dz][dy][2] = as_h2(q1.x); v[dz][dy][3] = as_h2(q1.y);
                }
#pragma unroll
            for (int oo = 0; oo < 4; ++oo) {
                const uint* wp = &wh3[((cog * 4 + oo) * 4 + cp) * 27];
#pragma unroll
                for (int kz = 0; kz < 3; ++kz)
#pragma unroll
                    for (int ky = 0; ky < 3; ++ky)
#pragma unroll
                        for (int kx = 0; kx < 3; ++kx) {
                            const half2_t wv = as_h2(wp[kz * 9 + ky * 3 + kx]);
#pragma unroll
                            for (int pz = 0; pz < 2; ++pz)
#pragma unroll
                                for (int py = 0; py < 2; ++py)
#pragma unroll
                                    for (int px = 0; px < 2; ++px)
                                        acc[oo][pz * 4 + py * 2 + px] =
                                            fdot2(v[pz + kz][py + ky][px + kx],
                                                  wv, acc[oo][pz * 4 + py * 2 + px]);
                        }
            }
        }
        const int hbase = (((zp + 1) * 6 + (yp + 1)) * 6 + (xp + 1)) << 4;
#pragma unroll
        for (int oo = 0; oo < 4; ++oo) {
            const int co = cog * 4 + oo;
            float m = acc[oo][0];
#pragma unroll
            for (int p = 1; p < 8; ++p) m = fmaxf(m, acc[oo][p]);
            s3h[hbase + co] = (_Float16)lrelu(m + cb3[co]);
        }
    }
    __syncthreads();

    // ---- L4: pos8 x co32, 1 output/thread; v reads broadcast across co ----
    {
        const int co = t >> 3;
        const int pos = t & 7;
        const int xp = pos & 1;
        const int yp = (pos >> 1) & 1;
        const int zp = pos >> 2;
        float acc[8];
#pragma unroll
        for (int p = 0; p < 8; ++p) acc[p] = 0.f;
#pragma unroll 1
        for (int c = 0; c < 8; ++c) {
            half2_t v[4][4][4];
#pragma unroll
            for (int dz = 0; dz < 4; ++dz)
#pragma unroll
                for (int dy = 0; dy < 4; ++dy)
#pragma unroll
                    for (int dx = 0; dx < 4; ++dx)
                        v[dz][dy][dx] = as_h2(sm[S3OUT +
                            ((((2 * zp + dz) * 6 + 2 * yp + dy) * 6 +
                              (2 * xp + dx)) << 3) + c]);
            const uint* wp = &wh4[(co * 8 + c) * 27];
#pragma unroll
            for (int kz = 0; kz < 3; ++kz)
#pragma unroll
                for (int ky = 0; ky < 3; ++ky)
#pragma unroll
                    for (int kx = 0; kx < 3; ++kx) {
                        const half2_t wv = as_h2(wp[kz * 9 + ky * 3 + kx]);
#pragma unroll
                        for (int pz = 0; pz < 2; ++pz)
#pragma unroll
                            for (int py = 0; py < 2; ++py)
#pragma unroll
                                for (int px = 0; px < 2; ++px)
                                    acc[pz * 4 + py * 2 + px] =
                                        fdot2(v[pz + kz][py + ky][px + kx], wv,
                                              acc[pz * 4 + py * 2 + px]);
                    }
        }
        float m = acc[0];
#pragma unroll
        for (int p = 1; p < 8; ++p) m = fmaxf(m, acc[p]);
        s4h[((((zp + 1) * 4 + (yp + 1)) * 4 + (xp + 1)) << 5) + co] =
            (_Float16)lrelu(m + cb4[co]);
    }
    __syncthreads();

    // ---- L5: co64 x cq4 partials (v reads full-wave broadcast) ----
    {
        const int co = t & 63;
        const int cq = __builtin_amdgcn_readfirstlane(t >> 6);
        float acc[8];
#pragma unroll
        for (int p = 0; p < 8; ++p) acc[p] = 0.f;
#pragma unroll 1
        for (int ci = 0; ci < 4; ++ci) {
            const int c = cq * 4 + ci;
            half2_t v[4][4][4];
#pragma unroll
            for (int dz = 0; dz < 4; ++dz)
#pragma unroll
                for (int dy = 0; dy < 4; ++dy)
#pragma unroll
                    for (int dx = 0; dx < 4; ++dx)
                        v[dz][dy][dx] = as_h2(sm[S4OUT +
                            (((dz * 4 + dy) * 4 + dx) << 4) + c]);
            const uint* wp = &wh5[(co * 16 + c) * 27];
#pragma unroll
            for (int kz = 0; kz < 3; ++kz)
#pragma unroll
                for (int ky = 0; ky < 3; ++ky)
#pragma unroll
                    for (int kx = 0; kx < 3; ++kx) {
                        const half2_t wv = as_h2(wp[kz * 9 + ky * 3 + kx]);
#pragma unroll
                        for (int pz = 0; pz < 2; ++pz)
#pragma unroll
                            for (int py = 0; py < 2; ++py)
#pragma unroll
                                for (int px = 0; px < 2; ++px)
                                    acc[pz * 4 + py * 2 + px] =
                                        fdot2(v[pz + kz][py + ky][px + kx], wv,
                                              acc[pz * 4 + py * 2 + px]);
                    }
        }
        // partials -> LDS (reuse S3IN area), stride 9 to avoid conflicts
#pragma unroll
        for (int p = 0; p < 8; ++p)
            smf[(cq * 64 + co) * 9 + p] = acc[p];
    }
    __syncthreads();

    // ---- L5 reduce: 64 threads ----
    if (t < 64) {
        float acc[8];
#pragma unroll
        for (int p = 0; p < 8; ++p)
            acc[p] = smf[t * 9 + p] + smf[(64 + t) * 9 + p] +
                     smf[(128 + t) * 9 + p] + smf[(192 + t) * 9 + p];
        float m = acc[0];
#pragma unroll
        for (int p = 1; p < 8; ++p) m = fmaxf(m, acc[p]);
        smf[FEAT + t] = lrelu(m + cb5[t]);
    }
    __syncthreads();

    // ---- FC1: 192 threads = h6 x j32 ----
    if (t < 192) {
        const int j = t & 31;
        const int h = t >> 5;
        float s = fb1[h * 32 + j];
#pragma unroll
        for (int k = 0; k < 64; ++k)
            s += smf[FEAT + k] * W1[(h * 64 + k) * 32 + j];
        smf[H1O + h * 32 + j] = lrelu(s);
    }
    __syncthreads();

    // ---- FC2: 96 threads ----
    if (t < 96) {
        const int j = t & 15;
        const int h = t >> 4;
        float s = fb2[h * 16 + j];
#pragma unroll
        for (int k = 0; k < 32; ++k)
            s += smf[H1O + h * 32 + k] * W2[(h * 32 + k) * 16 + j];
        smf[H2O + h * 16 + j] = lrelu(s);
    }
    __syncthreads();

    // ---- FC3: 24 threads ----
    if (t < 24) {
        const int j = t & 3;
        const int h = t >> 2;
        float s = fb3[h * 4 + j];
#pragma unroll
        for (int k = 0; k < 16; ++k)
            s += smf[H2O + h * 16 + k] * W3[(h * 16 + k) * 4 + j];
        smf[H3O + h * 4 + j] = lrelu(s);
    }
    __syncthreads();

    // ---- normalize + store ----
    if (t < 24) {
        const int q = t & 3;
        const int h = t >> 2;
        const float x0 = smf[H3O + h * 4 + 0];
        const float x1 = smf[H3O + h * 4 + 1];
        const float x2 = smf[H3O + h * 4 + 2];
        const float x3 = smf[H3O + h * 4 + 3];
        const float inv = 1.f / sqrtf(x0 * x0 + x1 * x1 + x2 * x2 + x3 * x3);
        out[(b * 6 + h) * 4 + q] = smf[H3O + h * 4 + q] * inv;
    }
}

// ---------------------------------------------------------------------------
// Weight pre-pack: fp32 [CO][CI][27] -> half2 [CO][CI/2][27] (pairs over ci).
// ---------------------------------------------------------------------------
__device__ __forceinline__ void pack_one(int i, const float* w, uint* h,
                                         int CO, int CI)
{
    const int CIH = CI / 2;
    const int n = CO * CIH * 27;
    if (i < n) {
        const int tap = i % 27;
        const int r   = i / 27;
        const int cp  = r % CIH;
        const int co  = r / CIH;
        const float* s = w + ((co * CI + 2 * cp) * 27 + tap);
        union { uint u; half2_t v; } c;
        c.v.x = (_Float16)s[0];
        c.v.y = (_Float16)s[27];
        h[i] = c.u;
    }
}

__global__ __launch_bounds__(256) void pack_weights(
    const float* w2, const float* w3, const float* w4, const float* w5,
    uint* h2, uint* h3, uint* h4, uint* h5)
{
    const int i = blockIdx.x * 256 + threadIdx.x;
    pack_one(i, w2, h2, 8, 4);
    pack_one(i, w3, h3, 16, 8);
    pack_one(i, w4, h4, 32, 16);
    pack_one(i, w5, h5, 64, 32);
}

extern "C" void kernel_launch(void* const* d_in, const int* in_sizes, int n_in,
                              void* d_out, int out_size, void* d_ws, size_t ws_size,
                              hipStream_t stream)
{
    const float* voxel = (const float*)d_in[0];
    const float* cw1 = (const float*)d_in[1];  const float* cb1 = (const float*)d_in[2];
    const float* cw2 = (const float*)d_in[3];  const float* cb2 = (const float*)d_in[4];
    const float* cw3 = (const float*)d_in[5];  const float* cb3 = (const float*)d_in[6];
    const float* cw4 = (const float*)d_in[7];  const float* cb4 = (const float*)d_in[8];
    const float* cw5 = (const float*)d_in[9];  const float* cb5 = (const float*)d_in[10];
    const float* W1  = (const float*)d_in[11]; const float* b1  = (const float*)d_in[12];
    const float* W2  = (const float*)d_in[13]; const float* b2  = (const float*)d_in[14];
    const float* W3  = (const float*)d_in[15]; const float* b3  = (const float*)d_in[16];
    float* out = (float*)d_out;

    const int B = 1024;
    uint* buf1h = (uint*)d_ws;                 // [1024][2][16^3]  8388608 w
    uint* buf2h = buf1h + 8388608;             // [1024][4][8^3]   2097152 w
    uint* wh2   = buf2h + 2097152;             // 432
    uint* wh3   = wh2 + 432;                   // 1728
    uint* wh4   = wh3 + 1728;                  // 6912
    uint* wh5   = wh4 + 6912;                  // 27648

    pack_weights<<<108, 256, 0, stream>>>(cw2, cw3, cw4, cw5, wh2, wh3, wh4, wh5);

    // L1: 1->4, 32^3->16^3 (fp32 compute, 128-VGPR budget)
    conv_pool_f32h<1, 4, 32, 2, 2, 4, 1><<<1024 * 8, 256, 0, stream>>>(
        voxel, cw1, cb1, (half2_t*)buf1h, B);
    // L2: CIH=2, 16^3->8^3 (dot2)
    conv_pool_h2<2, 8, 16, 2, 2, 4, 2><<<512 * 4, 256, 0, stream>>>(
        (const half2_t*)buf1h, wh2, cb2, (half2_t*)buf2h, B);
    // L3+L4+L5+FC fused v2: 1 batch/block
    tail_fused2<<<1024, 256, 0, stream>>>(
        buf2h, wh3, wh4, wh5, cb3, cb4, cb5,
        W1, b1, W2, b2, W3, b3, out);
}